// Round 2
// baseline (70601.697 us; speedup 1.0000x reference)
//
#include <hip/hip_runtime.h>
#include <hip/hip_bf16.h>
#include <math.h>

#define HIDDEN 256
#define SEQ 2048
#define BATCH 64
#define INSZ 128
#define OUTSZ 64
#define DTC 0.05f
#define CH 16
#define NCH 128   // SEQ/CH

// ---------------- zero flags ----------------
__global__ void zero_kernel(int* p, int n) {
    int i = blockIdx.x * 256 + threadIdx.x;
    if (i < n) p[i] = 0;
}

// ---------------- K0: complexity net + alphas ----------------
__global__ __launch_bounds__(1024) void prep_kernel(
    const float* __restrict__ x, const float* __restrict__ cw1, const float* __restrict__ cb1,
    const float* __restrict__ cw2, const float* __restrict__ cb2,
    const float* __restrict__ tau_b, const float* __restrict__ tmw, const float* __restrict__ tmb,
    float* __restrict__ alphas)   // [3][64]
{
    __shared__ float p_lds[8][128];
    __shared__ float xm[128];
    __shared__ float t1[64];
    int b = blockIdx.x;
    int tid = threadIdx.x;
    int c = tid & 127, sh = tid >> 7;
    const float* xb = x + (size_t)b * SEQ * INSZ;
    float s = 0.f;
    for (int t = sh * 256; t < (sh + 1) * 256; ++t) s += xb[(size_t)t * INSZ + c];
    p_lds[sh][c] = s;
    __syncthreads();
    if (tid < 128) {
        float m = 0.f;
        #pragma unroll
        for (int i = 0; i < 8; ++i) m += p_lds[i][tid];
        xm[tid] = m / (float)SEQ;
    }
    __syncthreads();
    if (tid < 64) {
        float acc = cb1[tid];
        for (int k = 0; k < 128; ++k) acc += xm[k] * cw1[tid * 128 + k];
        t1[tid] = fmaxf(acc, 0.f);
    }
    __syncthreads();
    if (tid == 0) {
        float acc = cb2[0];
        for (int k = 0; k < 64; ++k) acc += t1[k] * cw2[k];
        float comp = 1.f / (1.f + expf(-acc));
        for (int i = 0; i < 3; ++i) {
            float lg[4], mx = -1e30f;
            for (int j = 0; j < 4; ++j) { lg[j] = comp * tmw[i * 4 + j] + tmb[i * 4 + j]; mx = fmaxf(mx, lg[j]); }
            float den = 0.f;
            for (int j = 0; j < 4; ++j) { lg[j] = expf(lg[j] - mx); den += lg[j]; }
            float mt = 0.f;
            for (int j = 0; j < 4; ++j) mt += tau_b[i * 4 + j] * (lg[j] / den);
            alphas[i * 64 + b] = expf(-DTC / mt);
        }
    }
}

// ---------------- Wf = W_in0 @ pw  (256x128), bf = W_in0 @ pb + bias0 ----------------
__global__ __launch_bounds__(128) void wf_kernel(
    const float* __restrict__ W_in0, const float* __restrict__ pw,
    const float* __restrict__ pb, const float* __restrict__ bias0,
    float* __restrict__ Wf, float* __restrict__ bf)
{
    __shared__ float wrow[256];
    int j = blockIdx.x, k = threadIdx.x;
    for (int m = k; m < 256; m += 128) wrow[m] = W_in0[j * 256 + m];
    __syncthreads();
    float s = 0.f;
    for (int m = 0; m < 256; ++m) s = fmaf(wrow[m], pw[m * 128 + k], s);
    Wf[j * 128 + k] = s;
    if (k == 0) {
        float sb = bias0[j];
        for (int m = 0; m < 256; ++m) sb = fmaf(wrow[m], pb[m], sb);
        bf[j] = sb;
    }
}

__device__ __forceinline__ float fast_tanh(float x) {
    float ex = __expf(2.f * x);                 // v_exp based
    float r = __builtin_amdgcn_rcpf(ex + 1.f);  // v_rcp_f32
    return 1.f - 2.f * r;                       // ex=inf -> 1, ex=0 -> -1
}

// ---------------- fused per-layer kernel: 64 scan WGs + 192 ext-GEMM workers ----------------
// buf: [64][2048][256]  holds ext (written by workers) then h (in-place by scan)
// src: worker input, h_{i-1} (==buf, read-before-overwrite) or x for layer 0
template<int KDIM>
__global__ __launch_bounds__(512, 2) void layer_kernel(
    float* __restrict__ buf,
    const float* __restrict__ src,
    const float* __restrict__ W_ext,   // [256][KDIM]
    const float* __restrict__ ext_b,   // [256]
    const float* __restrict__ W_rec,   // [256][256]
    const float* __restrict__ alph,    // [64]
    float* __restrict__ h_carry,       // [64][256]
    int* __restrict__ flags,           // [64][NCH]
    int store_h, int first_layer)
{
    __shared__ float smem[CH * 256];   // worker: h-stage [CH][KDIM]; scan: h_lds[2][256]
    int tid = threadIdx.x;

    if (blockIdx.x < 64) {
        // ================= SCAN =================
        float* h_lds = smem;           // [2][256]
        int b = blockIdx.x;
        int o = tid >> 1, half = tid & 1;

        float4 wr[32];
        const float4* wp = (const float4*)(W_rec + (size_t)o * 256 + half * 128);
        #pragma unroll
        for (int m = 0; m < 32; ++m) wr[m] = wp[m];

        float alpha = alph[b];
        float onema = 1.f - alpha;
        float h = first_layer ? 0.f : h_carry[b * 256 + o];
        h_lds[o] = h;                                   // buffer 0
        float* bb = buf + (size_t)b * SEQ * HIDDEN;
        int* flg = flags + b * NCH;

        int cur = 0;
        float e_cur = 0.f;
        for (int c = 0; c < NCH; ++c) {
            if (tid == 0) {
                while (__hip_atomic_load(flg + c, __ATOMIC_ACQUIRE, __HIP_MEMORY_SCOPE_AGENT) == 0)
                    __builtin_amdgcn_s_sleep(2);
                int c2 = (c + 1 < NCH) ? c + 1 : c;
                while (__hip_atomic_load(flg + c2, __ATOMIC_ACQUIRE, __HIP_MEMORY_SCOPE_AGENT) == 0)
                    __builtin_amdgcn_s_sleep(2);
                __threadfence();   // agent acquire: invalidate stale L1/L2 lines
            }
            __syncthreads();
            if (c == 0) e_cur = bb[o];   // ext[0][o], now safe

            for (int tt = 0; tt < CH; ++tt) {
                int t = c * CH + tt;
                float e_n = 0.f;
                if (t + 1 < SEQ) e_n = bb[(size_t)(t + 1) * HIDDEN + o];  // prefetch (flag c+1 verified)

                float a0 = 0.f, a1 = 0.f, a2 = 0.f, a3 = 0.f;
                const float4* hp = (const float4*)(h_lds + cur * 256 + half * 128);
                #pragma unroll
                for (int m = 0; m < 32; m += 4) {
                    float4 h0 = hp[m], h1 = hp[m + 1], h2 = hp[m + 2], h3 = hp[m + 3];
                    a0 = fmaf(wr[m].x, h0.x, a0); a0 = fmaf(wr[m].y, h0.y, a0);
                    a0 = fmaf(wr[m].z, h0.z, a0); a0 = fmaf(wr[m].w, h0.w, a0);
                    a1 = fmaf(wr[m+1].x, h1.x, a1); a1 = fmaf(wr[m+1].y, h1.y, a1);
                    a1 = fmaf(wr[m+1].z, h1.z, a1); a1 = fmaf(wr[m+1].w, h1.w, a1);
                    a2 = fmaf(wr[m+2].x, h2.x, a2); a2 = fmaf(wr[m+2].y, h2.y, a2);
                    a2 = fmaf(wr[m+2].z, h2.z, a2); a2 = fmaf(wr[m+2].w, h2.w, a2);
                    a3 = fmaf(wr[m+3].x, h3.x, a3); a3 = fmaf(wr[m+3].y, h3.y, a3);
                    a3 = fmaf(wr[m+3].z, h3.z, a3); a3 = fmaf(wr[m+3].w, h3.w, a3);
                }
                float acc = (a0 + a1) + (a2 + a3);
                acc += __shfl_xor(acc, 1, 64);          // combine k-halves within lane pair
                float act = fast_tanh(acc + e_cur);
                h = alpha * h + onema * act;
                h_lds[(cur ^ 1) * 256 + o] = h;         // both lanes, same value
                if (store_h && half == 0) bb[(size_t)t * HIDDEN + o] = h;  // in-place h over consumed ext
                __syncthreads();                        // ONE barrier per step
                cur ^= 1;
                e_cur = e_n;
            }
        }
        if (half == 0) h_carry[b * 256 + o] = h;
    } else {
        // ================= EXT-GEMM WORKERS =================
        constexpr int MH = KDIM / 2;
        float* hstage = smem;          // [CH][KDIM]
        int wid = blockIdx.x - 64;     // 0..191
        int j = tid >> 1, kh = tid & 1;

        float4 wrk[MH / 4];
        const float4* wp = (const float4*)(W_ext + (size_t)j * KDIM + kh * MH);
        #pragma unroll
        for (int m = 0; m < MH / 4; ++m) wrk[m] = wp[m];
        float bj = ext_b[j];

        for (int u = wid; u < 64 * NCH; u += 192) {
            int c = u >> 6, b = u & 63;               // c-major ordering: early chunks first
            const float* sp = src + ((size_t)b * SEQ + c * CH) * KDIM;
            __syncthreads();                          // protect hstage from previous unit's readers
            for (int e = tid; e < CH * KDIM; e += 512) hstage[e] = sp[e];
            __syncthreads();

            float acc[CH];
            #pragma unroll
            for (int t = 0; t < CH; ++t) acc[t] = 0.f;
            #pragma unroll
            for (int m = 0; m < MH / 4; ++m) {
                float4 w = wrk[m];
                #pragma unroll
                for (int t = 0; t < CH; ++t) {
                    float4 hv = ((const float4*)(hstage + t * KDIM + kh * MH))[m];
                    acc[t] = fmaf(w.x, hv.x, acc[t]); acc[t] = fmaf(w.y, hv.y, acc[t]);
                    acc[t] = fmaf(w.z, hv.z, acc[t]); acc[t] = fmaf(w.w, hv.w, acc[t]);
                }
            }
            float* dst = buf + ((size_t)b * SEQ + c * CH) * HIDDEN;
            #pragma unroll
            for (int t = 0; t < CH; ++t) {
                float v = acc[t] + __shfl_xor(acc[t], 1, 64);
                if (kh == 0) dst[(size_t)t * HIDDEN + j] = v + bj;
            }
            __syncthreads();                          // all ext stores issued
            if (tid == 0) {
                __threadfence();                      // agent release: flush before flag
                __hip_atomic_store(&flags[b * NCH + c], 1, __ATOMIC_RELEASE, __HIP_MEMORY_SCOPE_AGENT);
            }
        }
    }
}

// ---------------- final projection from h_carry ----------------
__global__ __launch_bounds__(256) void outproj_kernel(
    const float* __restrict__ h_carry, const float* __restrict__ ow, const float* __restrict__ ob,
    float* __restrict__ out)
{
    __shared__ float h_l[256];
    __shared__ float p_lds[4][64];
    int b = blockIdx.x;
    int tid = threadIdx.x;
    h_l[tid] = h_carry[b * 256 + tid];
    __syncthreads();
    int o = tid & 63, qq = tid >> 6;
    float s = 0.f;
    const float4* wp = (const float4*)(ow + o * 256 + qq * 64);
    const float4* hp = (const float4*)(h_l + qq * 64);
    #pragma unroll
    for (int m = 0; m < 16; ++m) {
        float4 wv = wp[m]; float4 hv = hp[m];
        s = fmaf(wv.x, hv.x, s); s = fmaf(wv.y, hv.y, s);
        s = fmaf(wv.z, hv.z, s); s = fmaf(wv.w, hv.w, s);
    }
    p_lds[qq][o] = s;
    __syncthreads();
    if (tid < 64)
        out[b * 64 + tid] = p_lds[0][tid] + p_lds[1][tid] + p_lds[2][tid] + p_lds[3][tid] + ob[tid];
}

extern "C" void kernel_launch(void* const* d_in, const int* in_sizes, int n_in,
                              void* d_out, int out_size, void* d_ws, size_t ws_size,
                              hipStream_t stream)
{
    const float* x     = (const float*)d_in[0];
    const float* cw1   = (const float*)d_in[1];
    const float* cb1   = (const float*)d_in[2];
    const float* cw2   = (const float*)d_in[3];
    const float* cb2   = (const float*)d_in[4];
    const float* pw    = (const float*)d_in[5];
    const float* pb    = (const float*)d_in[6];
    const float* W_rec = (const float*)d_in[7];
    const float* W_in  = (const float*)d_in[8];
    const float* bias  = (const float*)d_in[9];
    const float* tau_b = (const float*)d_in[10];
    const float* tmw   = (const float*)d_in[11];
    const float* tmb   = (const float*)d_in[12];
    const float* ow    = (const float*)d_in[13];
    const float* ob    = (const float*)d_in[14];
    float* out = (float*)d_out;

    char* ws = (char*)d_ws;
    float* alphas  = (float*)ws;                       // 192 f
    float* h_carry = (float*)(ws + 4096);              // 64*256 f = 64KB
    float* bf      = (float*)(ws + 69632);             // 256 f
    int*   flags   = (int*)  (ws + 70656);             // 3*64*128 ints = 96KB
    float* Wf      = (float*)(ws + 168960);            // 256*128 f = 128KB
    float* buf     = (float*)(ws + 1048576);           // [64][2048][256] f32 = 134.2MB

    const int NFLAGS = 3 * BATCH * NCH;

    zero_kernel<<<(NFLAGS + 255) / 256, 256, 0, stream>>>(flags, NFLAGS);
    prep_kernel<<<64, 1024, 0, stream>>>(x, cw1, cb1, cw2, cb2, tau_b, tmw, tmb, alphas);
    wf_kernel<<<256, 128, 0, stream>>>(W_in, pw, pb, bias, Wf, bf);

    // layer 0: workers compute ext0 = x @ Wf.T + bf directly from x (proj fused)
    layer_kernel<128><<<256, 512, 0, stream>>>(buf, x, Wf, bf,
        W_rec, alphas, h_carry, flags, 1, 1);
    // layer 1
    layer_kernel<256><<<256, 512, 0, stream>>>(buf, buf,
        W_in + (size_t)1 * HIDDEN * HIDDEN, bias + 1 * HIDDEN,
        W_rec + (size_t)1 * HIDDEN * HIDDEN, alphas + 64, h_carry, flags + BATCH * NCH, 1, 0);
    // layer 2 (no h_seq stores needed)
    layer_kernel<256><<<256, 512, 0, stream>>>(buf, buf,
        W_in + (size_t)2 * HIDDEN * HIDDEN, bias + 2 * HIDDEN,
        W_rec + (size_t)2 * HIDDEN * HIDDEN, alphas + 128, h_carry, flags + 2 * BATCH * NCH, 0, 0);

    outproj_kernel<<<64, 256, 0, stream>>>(h_carry, ow, ob, out);
}

// Round 3
// 5341.230 us; speedup vs baseline: 13.2182x; 13.2182x over previous
//
#include <hip/hip_runtime.h>
#include <hip/hip_bf16.h>
#include <math.h>

#define HIDDEN 256
#define SEQ 2048
#define BATCH 64
#define INSZ 128
#define OUTSZ 64
#define DTC 0.05f

// ---------------- K0: complexity net + alphas ----------------
__global__ __launch_bounds__(1024) void prep_kernel(
    const float* __restrict__ x, const float* __restrict__ cw1, const float* __restrict__ cb1,
    const float* __restrict__ cw2, const float* __restrict__ cb2,
    const float* __restrict__ tau_b, const float* __restrict__ tmw, const float* __restrict__ tmb,
    float* __restrict__ alphas)   // [3][64]
{
    __shared__ float p_lds[8][128];
    __shared__ float xm[128];
    __shared__ float t1[64];
    int b = blockIdx.x;
    int tid = threadIdx.x;
    int c = tid & 127, sh = tid >> 7;
    const float* xb = x + (size_t)b * SEQ * INSZ;
    float s = 0.f;
    for (int t = sh * 256; t < (sh + 1) * 256; ++t) s += xb[(size_t)t * INSZ + c];
    p_lds[sh][c] = s;
    __syncthreads();
    if (tid < 128) {
        float m = 0.f;
        #pragma unroll
        for (int i = 0; i < 8; ++i) m += p_lds[i][tid];
        xm[tid] = m / (float)SEQ;
    }
    __syncthreads();
    if (tid < 64) {
        float acc = cb1[tid];
        for (int k = 0; k < 128; ++k) acc += xm[k] * cw1[tid * 128 + k];
        t1[tid] = fmaxf(acc, 0.f);
    }
    __syncthreads();
    if (tid == 0) {
        float acc = cb2[0];
        for (int k = 0; k < 64; ++k) acc += t1[k] * cw2[k];
        float comp = 1.f / (1.f + expf(-acc));
        for (int i = 0; i < 3; ++i) {
            float lg[4], mx = -1e30f;
            for (int j = 0; j < 4; ++j) { lg[j] = comp * tmw[i * 4 + j] + tmb[i * 4 + j]; mx = fmaxf(mx, lg[j]); }
            float den = 0.f;
            for (int j = 0; j < 4; ++j) { lg[j] = expf(lg[j] - mx); den += lg[j]; }
            float mt = 0.f;
            for (int j = 0; j < 4; ++j) mt += tau_b[i * 4 + j] * (lg[j] / den);
            alphas[i * 64 + b] = expf(-DTC / mt);
        }
    }
}

// ---------------- Wf = W_in0 @ pw  (256x128), bf = W_in0 @ pb + bias0 ----------------
__global__ __launch_bounds__(128) void wf_kernel(
    const float* __restrict__ W_in0, const float* __restrict__ pw,
    const float* __restrict__ pb, const float* __restrict__ bias0,
    float* __restrict__ Wf, float* __restrict__ bf)
{
    __shared__ float wrow[256];
    int j = blockIdx.x, k = threadIdx.x;
    for (int m = k; m < 256; m += 128) wrow[m] = W_in0[j * 256 + m];
    __syncthreads();
    float s = 0.f;
    for (int m = 0; m < 256; ++m) s = fmaf(wrow[m], pw[m * 128 + k], s);
    Wf[j * 128 + k] = s;
    if (k == 0) {
        float sb = bias0[j];
        for (int m = 0; m < 256; ++m) sb = fmaf(wrow[m], pb[m], sb);
        bf[j] = sb;
    }
}

// ---------------- streaming register-weight GEMM (proven in round 1) ----------------
template<int KQ, int NR>
__global__ __launch_bounds__(512) void gemm_stream(
    const float* A, const float* __restrict__ W, const float* __restrict__ bias,
    float* C, int rows_per_wg)
{
    constexpr int K = KQ * 64;
    constexpr int JB = 8 / KQ;
    __shared__ float a_lds[4 * K];
    __shared__ float p_lds[KQ][4][256];
    __shared__ float bias_l[256];
    int tid = threadIdx.x;
    int w = tid >> 6, l = tid & 63;
    int q = w % KQ, jb = w / KQ;

    float4 wr[NR][16];
    #pragma unroll
    for (int r = 0; r < NR; ++r) {
        int j = jb * 64 + l + r * (JB * 64);
        const float4* wp = (const float4*)(W + (size_t)j * K + q * 64);
        #pragma unroll
        for (int m = 0; m < 16; ++m) wr[r][m] = wp[m];
    }
    if (tid < 256) bias_l[tid] = bias[tid];

    size_t row0 = (size_t)blockIdx.x * rows_per_wg;
    for (int it = 0; it < rows_per_wg; it += 4) {
        size_t m0 = row0 + it;
        __syncthreads();
        #pragma unroll
        for (int e = 0; e < K / 128; ++e)
            a_lds[tid + e * 512] = A[m0 * K + tid + e * 512];
        __syncthreads();

        float acc[4][NR];
        #pragma unroll
        for (int r4 = 0; r4 < 4; ++r4)
            #pragma unroll
            for (int r = 0; r < NR; ++r) acc[r4][r] = 0.f;

        #pragma unroll
        for (int r4 = 0; r4 < 4; ++r4) {
            const float4* hp = (const float4*)(a_lds + r4 * K + q * 64);
            #pragma unroll
            for (int m = 0; m < 16; ++m) {
                float4 hv = hp[m];
                #pragma unroll
                for (int r = 0; r < NR; ++r) {
                    acc[r4][r] = fmaf(wr[r][m].x, hv.x, acc[r4][r]);
                    acc[r4][r] = fmaf(wr[r][m].y, hv.y, acc[r4][r]);
                    acc[r4][r] = fmaf(wr[r][m].z, hv.z, acc[r4][r]);
                    acc[r4][r] = fmaf(wr[r][m].w, hv.w, acc[r4][r]);
                }
            }
        }
        #pragma unroll
        for (int r4 = 0; r4 < 4; ++r4)
            #pragma unroll
            for (int r = 0; r < NR; ++r)
                p_lds[q][r4][jb * 64 + l + r * (JB * 64)] = acc[r4][r];
        __syncthreads();
        if (tid < 256) {
            #pragma unroll
            for (int r4 = 0; r4 < 4; ++r4) {
                float s2 = bias_l[tid];
                #pragma unroll
                for (int qq = 0; qq < KQ; ++qq) s2 += p_lds[qq][r4][tid];
                C[(m0 + r4) * 256 + tid] = s2;
            }
        }
    }
}

__device__ __forceinline__ float fast_tanh(float x) {
    float ex = __expf(2.f * x);                 // v_exp based
    float r = __builtin_amdgcn_rcpf(ex + 1.f);  // v_rcp_f32
    return 1.f - 2.f * r;                       // ex=inf -> 1, ex=0 -> -1
}

// ---------------- scan: one WG per batch element, R=4 x S=32 butterfly ----------------
// thread t: group g = t>>3 (4 outputs o = 4g..4g+3), k-segment kq = t&7 (k in [32kq,32kq+32))
// h_lds padded: logical f -> phys f + (f>>5)*4, so the 8 segment bases hit disjoint banks.
__global__ __launch_bounds__(512) void scan_kernel(
    float* buf,                       // [B][S][256]: in = ext, out = h_seq (in place)
    const float* __restrict__ W_rec,  // [256][256]
    const float* __restrict__ alphas, // [64]
    float* __restrict__ h_carry,      // [64][256]
    int layer, int write_all)
{
    __shared__ float h_lds[2][288];   // 8 segs * 36 floats
    int b = blockIdx.x;
    int tid = threadIdx.x;
    int g = tid >> 3;       // 0..63
    int kq = tid & 7;       // 0..7
    int j = kq & 3;         // output this lane finalizes
    int o = g * 4 + j;
    int wphys = o + ((o >> 5) << 2);

    // weights: rows 4g..4g+3, cols [32kq, 32kq+32)
    float4 wr[4][8];
    #pragma unroll
    for (int jj = 0; jj < 4; ++jj) {
        const float4* wp = (const float4*)(W_rec + (size_t)(g * 4 + jj) * 256 + kq * 32);
        #pragma unroll
        for (int m = 0; m < 8; ++m) wr[jj][m] = wp[m];
    }

    float alpha = alphas[b];
    float onema = 1.f - alpha;
    float* bb = buf + (size_t)b * SEQ * HIDDEN;

    float h_reg = (layer == 0) ? 0.f : h_carry[b * 256 + o];
    if (kq < 4) h_lds[0][wphys] = h_reg;
    float e_cur = bb[o];   // ext[0][o]
    __syncthreads();

    int cur = 0;
    for (int t = 0; t < SEQ; ++t) {
        float e_n = 0.f;
        if (t + 1 < SEQ) e_n = bb[(size_t)(t + 1) * HIDDEN + o];  // prefetch

        const float4* hp = (const float4*)(&h_lds[cur][kq * 36]);
        float a0 = 0.f, a1 = 0.f, a2 = 0.f, a3 = 0.f;
        #pragma unroll
        for (int m = 0; m < 8; ++m) {
            float4 hv = hp[m];
            a0 = fmaf(wr[0][m].x, hv.x, a0); a0 = fmaf(wr[0][m].y, hv.y, a0);
            a0 = fmaf(wr[0][m].z, hv.z, a0); a0 = fmaf(wr[0][m].w, hv.w, a0);
            a1 = fmaf(wr[1][m].x, hv.x, a1); a1 = fmaf(wr[1][m].y, hv.y, a1);
            a1 = fmaf(wr[1][m].z, hv.z, a1); a1 = fmaf(wr[1][m].w, hv.w, a1);
            a2 = fmaf(wr[2][m].x, hv.x, a2); a2 = fmaf(wr[2][m].y, hv.y, a2);
            a2 = fmaf(wr[2][m].z, hv.z, a2); a2 = fmaf(wr[2][m].w, hv.w, a2);
            a3 = fmaf(wr[3][m].x, hv.x, a3); a3 = fmaf(wr[3][m].y, hv.y, a3);
            a3 = fmaf(wr[3][m].z, hv.z, a3); a3 = fmaf(wr[3][m].w, hv.w, a3);
        }
        // butterfly over the 8-lane k-group: after this every lane has all 4 full dots
        #pragma unroll
        for (int msk = 1; msk <= 4; msk <<= 1) {
            a0 += __shfl_xor(a0, msk, 64);
            a1 += __shfl_xor(a1, msk, 64);
            a2 += __shfl_xor(a2, msk, 64);
            a3 += __shfl_xor(a3, msk, 64);
        }
        float acc = (j == 0) ? a0 : (j == 1) ? a1 : (j == 2) ? a2 : a3;
        float act = fast_tanh(acc + e_cur);
        h_reg = alpha * h_reg + onema * act;
        if (kq < 4) h_lds[cur ^ 1][wphys] = h_reg;                 // LDS for next step
        else if (write_all) bb[(size_t)t * HIDDEN + o] = h_reg;    // global h (in place)
        __syncthreads();
        cur ^= 1;
        e_cur = e_n;
    }
    if (kq >= 4) h_carry[b * 256 + o] = h_reg;
}

// ---------------- final projection from h_carry ----------------
__global__ __launch_bounds__(256) void outproj_kernel(
    const float* __restrict__ h_carry, const float* __restrict__ ow, const float* __restrict__ ob,
    float* __restrict__ out)
{
    __shared__ float h_l[256];
    __shared__ float p_lds[4][64];
    int b = blockIdx.x;
    int tid = threadIdx.x;
    h_l[tid] = h_carry[b * 256 + tid];
    __syncthreads();
    int o = tid & 63, qq = tid >> 6;
    float s = 0.f;
    const float4* wp = (const float4*)(ow + o * 256 + qq * 64);
    const float4* hp = (const float4*)(h_l + qq * 64);
    #pragma unroll
    for (int m = 0; m < 16; ++m) {
        float4 wv = wp[m]; float4 hv = hp[m];
        s = fmaf(wv.x, hv.x, s); s = fmaf(wv.y, hv.y, s);
        s = fmaf(wv.z, hv.z, s); s = fmaf(wv.w, hv.w, s);
    }
    p_lds[qq][o] = s;
    __syncthreads();
    if (tid < 64)
        out[b * 64 + tid] = p_lds[0][tid] + p_lds[1][tid] + p_lds[2][tid] + p_lds[3][tid] + ob[tid];
}

extern "C" void kernel_launch(void* const* d_in, const int* in_sizes, int n_in,
                              void* d_out, int out_size, void* d_ws, size_t ws_size,
                              hipStream_t stream)
{
    const float* x     = (const float*)d_in[0];
    const float* cw1   = (const float*)d_in[1];
    const float* cb1   = (const float*)d_in[2];
    const float* cw2   = (const float*)d_in[3];
    const float* cb2   = (const float*)d_in[4];
    const float* pw    = (const float*)d_in[5];
    const float* pb    = (const float*)d_in[6];
    const float* W_rec = (const float*)d_in[7];
    const float* W_in  = (const float*)d_in[8];
    const float* bias  = (const float*)d_in[9];
    const float* tau_b = (const float*)d_in[10];
    const float* tmw   = (const float*)d_in[11];
    const float* tmb   = (const float*)d_in[12];
    const float* ow    = (const float*)d_in[13];
    const float* ob    = (const float*)d_in[14];
    float* out = (float*)d_out;

    char* ws = (char*)d_ws;
    float* alphas  = (float*)ws;                       // 192 f
    float* h_carry = (float*)(ws + 4096);              // 64*256 f
    float* bf      = (float*)(ws + 69632);             // 256 f
    float* Wf      = (float*)(ws + 70656);             // 256*128 f
    float* buf     = (float*)(ws + 1048576);           // [64][2048][256] f32 = 134.2MB

    const int M = BATCH * SEQ;          // 131072 rows
    const int ROWS_PER_WG = M / 256;    // 512

    prep_kernel<<<64, 1024, 0, stream>>>(x, cw1, cb1, cw2, cb2, tau_b, tmw, tmb, alphas);
    wf_kernel<<<256, 128, 0, stream>>>(W_in, pw, pb, bias, Wf, bf);

    // layer 0 ext = x @ Wf.T + bf  (input projection fused away)
    gemm_stream<2, 1><<<256, 512, 0, stream>>>(x, Wf, bf, buf, ROWS_PER_WG);
    scan_kernel<<<64, 512, 0, stream>>>(buf, W_rec, alphas, h_carry, 0, 1);

    gemm_stream<4, 2><<<256, 512, 0, stream>>>(buf, W_in + (size_t)1 * HIDDEN * HIDDEN,
                                               bias + 1 * HIDDEN, buf, ROWS_PER_WG);
    scan_kernel<<<64, 512, 0, stream>>>(buf, W_rec + (size_t)1 * HIDDEN * HIDDEN,
                                        alphas + 64, h_carry, 1, 1);

    gemm_stream<4, 2><<<256, 512, 0, stream>>>(buf, W_in + (size_t)2 * HIDDEN * HIDDEN,
                                               bias + 2 * HIDDEN, buf, ROWS_PER_WG);
    scan_kernel<<<64, 512, 0, stream>>>(buf, W_rec + (size_t)2 * HIDDEN * HIDDEN,
                                        alphas + 128, h_carry, 2, 0);

    outproj_kernel<<<64, 256, 0, stream>>>(h_carry, ow, ob, out);
}

// Round 5
// 4313.897 us; speedup vs baseline: 16.3661x; 1.2381x over previous
//
#include <hip/hip_runtime.h>
#include <hip/hip_bf16.h>
#include <math.h>

#define HIDDEN 256
#define SEQ 2048
#define BATCH 64
#define INSZ 128
#define OUTSZ 64
#define DTC 0.05f

typedef _Float16 h2 __attribute__((ext_vector_type(2)));

// ---------------- K0: complexity net + alphas ----------------
__global__ __launch_bounds__(1024) void prep_kernel(
    const float* __restrict__ x, const float* __restrict__ cw1, const float* __restrict__ cb1,
    const float* __restrict__ cw2, const float* __restrict__ cb2,
    const float* __restrict__ tau_b, const float* __restrict__ tmw, const float* __restrict__ tmb,
    float* __restrict__ alphas)   // [3][64]
{
    __shared__ float p_lds[8][128];
    __shared__ float xm[128];
    __shared__ float t1[64];
    int b = blockIdx.x;
    int tid = threadIdx.x;
    int c = tid & 127, sh = tid >> 7;
    const float* xb = x + (size_t)b * SEQ * INSZ;
    float s = 0.f;
    for (int t = sh * 256; t < (sh + 1) * 256; ++t) s += xb[(size_t)t * INSZ + c];
    p_lds[sh][c] = s;
    __syncthreads();
    if (tid < 128) {
        float m = 0.f;
        #pragma unroll
        for (int i = 0; i < 8; ++i) m += p_lds[i][tid];
        xm[tid] = m / (float)SEQ;
    }
    __syncthreads();
    if (tid < 64) {
        float acc = cb1[tid];
        for (int k = 0; k < 128; ++k) acc += xm[k] * cw1[tid * 128 + k];
        t1[tid] = fmaxf(acc, 0.f);
    }
    __syncthreads();
    if (tid == 0) {
        float acc = cb2[0];
        for (int k = 0; k < 64; ++k) acc += t1[k] * cw2[k];
        float comp = 1.f / (1.f + expf(-acc));
        for (int i = 0; i < 3; ++i) {
            float lg[4], mx = -1e30f;
            for (int j = 0; j < 4; ++j) { lg[j] = comp * tmw[i * 4 + j] + tmb[i * 4 + j]; mx = fmaxf(mx, lg[j]); }
            float den = 0.f;
            for (int j = 0; j < 4; ++j) { lg[j] = expf(lg[j] - mx); den += lg[j]; }
            float mt = 0.f;
            for (int j = 0; j < 4; ++j) mt += tau_b[i * 4 + j] * (lg[j] / den);
            alphas[i * 64 + b] = expf(-DTC / mt);
        }
    }
}

// ---------------- Wf = W_in0 @ pw  (256x128), bf = W_in0 @ pb + bias0 ----------------
__global__ __launch_bounds__(128) void wf_kernel(
    const float* __restrict__ W_in0, const float* __restrict__ pw,
    const float* __restrict__ pb, const float* __restrict__ bias0,
    float* __restrict__ Wf, float* __restrict__ bf)
{
    __shared__ float wrow[256];
    int j = blockIdx.x, k = threadIdx.x;
    for (int m = k; m < 256; m += 128) wrow[m] = W_in0[j * 256 + m];
    __syncthreads();
    float s = 0.f;
    for (int m = 0; m < 256; ++m) s = fmaf(wrow[m], pw[m * 128 + k], s);
    Wf[j * 128 + k] = s;
    if (k == 0) {
        float sb = bias0[j];
        for (int m = 0; m < 256; ++m) sb = fmaf(wrow[m], pb[m], sb);
        bf[j] = sb;
    }
}

// ---------------- streaming register-weight GEMM (unchanged, fp32) ----------------
template<int KQ, int NR>
__global__ __launch_bounds__(512) void gemm_stream(
    const float* A, const float* __restrict__ W, const float* __restrict__ bias,
    float* C, int rows_per_wg)
{
    constexpr int K = KQ * 64;
    constexpr int JB = 8 / KQ;
    __shared__ float a_lds[4 * K];
    __shared__ float p_lds[KQ][4][256];
    __shared__ float bias_l[256];
    int tid = threadIdx.x;
    int w = tid >> 6, l = tid & 63;
    int q = w % KQ, jb = w / KQ;

    float4 wr[NR][16];
    #pragma unroll
    for (int r = 0; r < NR; ++r) {
        int j = jb * 64 + l + r * (JB * 64);
        const float4* wp = (const float4*)(W + (size_t)j * K + q * 64);
        #pragma unroll
        for (int m = 0; m < 16; ++m) wr[r][m] = wp[m];
    }
    if (tid < 256) bias_l[tid] = bias[tid];

    size_t row0 = (size_t)blockIdx.x * rows_per_wg;
    for (int it = 0; it < rows_per_wg; it += 4) {
        size_t m0 = row0 + it;
        __syncthreads();
        #pragma unroll
        for (int e = 0; e < K / 128; ++e)
            a_lds[tid + e * 512] = A[m0 * K + tid + e * 512];
        __syncthreads();

        float acc[4][NR];
        #pragma unroll
        for (int r4 = 0; r4 < 4; ++r4)
            #pragma unroll
            for (int r = 0; r < NR; ++r) acc[r4][r] = 0.f;

        #pragma unroll
        for (int r4 = 0; r4 < 4; ++r4) {
            const float4* hp = (const float4*)(a_lds + r4 * K + q * 64);
            #pragma unroll
            for (int m = 0; m < 16; ++m) {
                float4 hv = hp[m];
                #pragma unroll
                for (int r = 0; r < NR; ++r) {
                    acc[r4][r] = fmaf(wr[r][m].x, hv.x, acc[r4][r]);
                    acc[r4][r] = fmaf(wr[r][m].y, hv.y, acc[r4][r]);
                    acc[r4][r] = fmaf(wr[r][m].z, hv.z, acc[r4][r]);
                    acc[r4][r] = fmaf(wr[r][m].w, hv.w, acc[r4][r]);
                }
            }
        }
        #pragma unroll
        for (int r4 = 0; r4 < 4; ++r4)
            #pragma unroll
            for (int r = 0; r < NR; ++r)
                p_lds[q][r4][jb * 64 + l + r * (JB * 64)] = acc[r4][r];
        __syncthreads();
        if (tid < 256) {
            #pragma unroll
            for (int r4 = 0; r4 < 4; ++r4) {
                float s2 = bias_l[tid];
                #pragma unroll
                for (int qq = 0; qq < KQ; ++qq) s2 += p_lds[qq][r4][tid];
                C[(m0 + r4) * 256 + tid] = s2;
            }
        }
    }
}

__device__ __forceinline__ float fast_tanh(float x) {
    float ex = __expf(2.f * x);                 // v_exp based
    float r = __builtin_amdgcn_rcpf(ex + 1.f);  // v_rcp_f32
    return 1.f - 2.f * r;                       // ex=inf -> 1, ex=0 -> -1
}

// cross-lane add helpers: xor1/xor2 on VALU (DPP quad_perm), xor4 on ds_swizzle
__device__ __forceinline__ float dpp_add_xor1(float v) {
    int x = __builtin_amdgcn_update_dpp(0, __builtin_bit_cast(int, v), 0xB1, 0xF, 0xF, false); // quad_perm [1,0,3,2]
    return v + __builtin_bit_cast(float, x);
}
__device__ __forceinline__ float dpp_add_xor2(float v) {
    int x = __builtin_amdgcn_update_dpp(0, __builtin_bit_cast(int, v), 0x4E, 0xF, 0xF, false); // quad_perm [2,3,0,1]
    return v + __builtin_bit_cast(float, x);
}
__device__ __forceinline__ float swz_add_xor4(float v) {
    int x = __builtin_amdgcn_ds_swizzle(__builtin_bit_cast(int, v), 0x101F);  // xor 4, and 0x1F
    return v + __builtin_bit_cast(float, x);
}

#if __has_builtin(__builtin_amdgcn_fdot2)
#define FDOT2(a, b, c) __builtin_amdgcn_fdot2((a), (b), (c), false)
#else
#define FDOT2(a, b, c) fmaf((float)(a).x, (float)(b).x, fmaf((float)(a).y, (float)(b).y, (c)))
#endif

// ---------------- scan: T=8 k-segs x R=4 outs, f16 h in LDS, fdot2 MACs ----------------
// thread t: g = t>>3 (outputs 4g..4g+3), kq = t&7 (k in [32kq, 32kq+32))
// h16 seg stride 112B: bases kq*28 uints mod 32 = {0,28,24,20,16,12,8,4} -> conflict-free b128 reads
__global__ __launch_bounds__(512) void scan_kernel(
    float* buf,                       // [B][S][256]: in = ext, out = h_seq (in place)
    const float* __restrict__ W_rec,  // [256][256]
    const float* __restrict__ alphas, // [64]
    float* __restrict__ h_carry,      // [64][256]
    int layer, int write_all)
{
    __shared__ alignas(16) unsigned short h16[2][8 * 56];  // 2 x 896B
    int b = blockIdx.x;
    int tid = threadIdx.x;
    int g = tid >> 3;       // 0..63
    int kq = tid & 7;       // 0..7
    int j = kq & 3;         // which of the 4 outputs this lane finalizes
    int o = g * 4 + j;

    // weights rows 4g..4g+3, cols [32kq, 32kq+32), converted to 16 half2 per row
    h2 wh[4][16];
    #pragma unroll
    for (int jj = 0; jj < 4; ++jj) {
        const float4* wp = (const float4*)(W_rec + (size_t)(g * 4 + jj) * 256 + kq * 32);
        #pragma unroll
        for (int m = 0; m < 8; ++m) {
            float4 wv = wp[m];
            wh[jj][2 * m]     = __builtin_bit_cast(h2, __builtin_amdgcn_cvt_pkrtz(wv.x, wv.y));
            wh[jj][2 * m + 1] = __builtin_bit_cast(h2, __builtin_amdgcn_cvt_pkrtz(wv.z, wv.w));
        }
    }

    float alpha = alphas[b];
    float onema = 1.f - alpha;
    float* bb = buf + (size_t)b * SEQ * HIDDEN;

    float h_reg = (layer == 0) ? 0.f : h_carry[b * 256 + o];
    char* hbase = (char*)&h16[0][0];
    if (kq < 4)
        *(_Float16*)(hbase + (o >> 5) * 112 + (o & 31) * 2) = (_Float16)h_reg;
    float e_cur = bb[o];   // ext[0][o]
    __syncthreads();

    int cur = 0;
    for (int t = 0; t < SEQ; ++t) {
        float e_n = 0.f;
        if (t + 1 < SEQ) e_n = bb[(size_t)(t + 1) * HIDDEN + o];  // prefetch

        // read 32 f16 of h (this thread's k-segment): 4 x ds_read_b128
        const uint4* hp = (const uint4*)(hbase + cur * 896 + kq * 112);
        uint4 q0 = hp[0], q1 = hp[1], q2 = hp[2], q3 = hp[3];
        unsigned int hw[16] = {q0.x, q0.y, q0.z, q0.w, q1.x, q1.y, q1.z, q1.w,
                               q2.x, q2.y, q2.z, q2.w, q3.x, q3.y, q3.z, q3.w};

        float a0 = 0.f, a1 = 0.f, a2 = 0.f, a3 = 0.f;
        #pragma unroll
        for (int m = 0; m < 16; ++m) {
            h2 hv = __builtin_bit_cast(h2, hw[m]);
            a0 = FDOT2(wh[0][m], hv, a0);
            a1 = FDOT2(wh[1][m], hv, a1);
            a2 = FDOT2(wh[2][m], hv, a2);
            a3 = FDOT2(wh[3][m], hv, a3);
        }
        // reduce over the 8 k-segments: 1 ds_swizzle level + 2 DPP levels
        a0 = swz_add_xor4(a0); a1 = swz_add_xor4(a1); a2 = swz_add_xor4(a2); a3 = swz_add_xor4(a3);
        a0 = dpp_add_xor2(a0); a1 = dpp_add_xor2(a1); a2 = dpp_add_xor2(a2); a3 = dpp_add_xor2(a3);
        a0 = dpp_add_xor1(a0); a1 = dpp_add_xor1(a1); a2 = dpp_add_xor1(a2); a3 = dpp_add_xor1(a3);
        float acc = (j == 0) ? a0 : (j == 1) ? a1 : (j == 2) ? a2 : a3;

        float act = fast_tanh(acc + e_cur);
        h_reg = alpha * h_reg + onema * act;
        if (kq < 4)
            *(_Float16*)(hbase + (cur ^ 1) * 896 + (o >> 5) * 112 + (o & 31) * 2) = (_Float16)h_reg;
        else if (write_all)
            bb[(size_t)t * HIDDEN + o] = h_reg;    // in-place h over consumed ext
        __syncthreads();
        cur ^= 1;
        e_cur = e_n;
    }
    if (kq >= 4) h_carry[b * 256 + o] = h_reg;
}

// ---------------- final projection from h_carry ----------------
__global__ __launch_bounds__(256) void outproj_kernel(
    const float* __restrict__ h_carry, const float* __restrict__ ow, const float* __restrict__ ob,
    float* __restrict__ out)
{
    __shared__ float h_l[256];
    __shared__ float p_lds[4][64];
    int b = blockIdx.x;
    int tid = threadIdx.x;
    h_l[tid] = h_carry[b * 256 + tid];
    __syncthreads();
    int o = tid & 63, qq = tid >> 6;
    float s = 0.f;
    const float4* wp = (const float4*)(ow + o * 256 + qq * 64);
    const float4* hp = (const float4*)(h_l + qq * 64);
    #pragma unroll
    for (int m = 0; m < 16; ++m) {
        float4 wv = wp[m]; float4 hv = hp[m];
        s = fmaf(wv.x, hv.x, s); s = fmaf(wv.y, hv.y, s);
        s = fmaf(wv.z, hv.z, s); s = fmaf(wv.w, hv.w, s);
    }
    p_lds[qq][o] = s;
    __syncthreads();
    if (tid < 64)
        out[b * 64 + tid] = p_lds[0][tid] + p_lds[1][tid] + p_lds[2][tid] + p_lds[3][tid] + ob[tid];
}

extern "C" void kernel_launch(void* const* d_in, const int* in_sizes, int n_in,
                              void* d_out, int out_size, void* d_ws, size_t ws_size,
                              hipStream_t stream)
{
    const float* x     = (const float*)d_in[0];
    const float* cw1   = (const float*)d_in[1];
    const float* cb1   = (const float*)d_in[2];
    const float* cw2   = (const float*)d_in[3];
    const float* cb2   = (const float*)d_in[4];
    const float* pw    = (const float*)d_in[5];
    const float* pb    = (const float*)d_in[6];
    const float* W_rec = (const float*)d_in[7];
    const float* W_in  = (const float*)d_in[8];
    const float* bias  = (const float*)d_in[9];
    const float* tau_b = (const float*)d_in[10];
    const float* tmw   = (const float*)d_in[11];
    const float* tmb   = (const float*)d_in[12];
    const float* ow    = (const float*)d_in[13];
    const float* ob    = (const float*)d_in[14];
    float* out = (float*)d_out;

    char* ws = (char*)d_ws;
    float* alphas  = (float*)ws;                       // 192 f
    float* h_carry = (float*)(ws + 4096);              // 64*256 f
    float* bf      = (float*)(ws + 69632);             // 256 f
    float* Wf      = (float*)(ws + 70656);             // 256*128 f
    float* buf     = (float*)(ws + 1048576);           // [64][2048][256] f32 = 134.2MB

    const int M = BATCH * SEQ;          // 131072 rows
    const int ROWS_PER_WG = M / 256;    // 512

    prep_kernel<<<64, 1024, 0, stream>>>(x, cw1, cb1, cw2, cb2, tau_b, tmw, tmb, alphas);
    wf_kernel<<<256, 128, 0, stream>>>(W_in, pw, pb, bias, Wf, bf);

    // layer 0 ext = x @ Wf.T + bf  (input projection fused away)
    gemm_stream<2, 1><<<256, 512, 0, stream>>>(x, Wf, bf, buf, ROWS_PER_WG);
    scan_kernel<<<64, 512, 0, stream>>>(buf, W_rec, alphas, h_carry, 0, 1);

    gemm_stream<4, 2><<<256, 512, 0, stream>>>(buf, W_in + (size_t)1 * HIDDEN * HIDDEN,
                                               bias + 1 * HIDDEN, buf, ROWS_PER_WG);
    scan_kernel<<<64, 512, 0, stream>>>(buf, W_rec + (size_t)1 * HIDDEN * HIDDEN,
                                        alphas + 64, h_carry, 1, 1);

    gemm_stream<4, 2><<<256, 512, 0, stream>>>(buf, W_in + (size_t)2 * HIDDEN * HIDDEN,
                                               bias + 2 * HIDDEN, buf, ROWS_PER_WG);
    scan_kernel<<<64, 512, 0, stream>>>(buf, W_rec + (size_t)2 * HIDDEN * HIDDEN,
                                        alphas + 128, h_carry, 2, 0);

    outproj_kernel<<<64, 256, 0, stream>>>(h_carry, ow, ob, out);
}

// Round 6
// 3856.923 us; speedup vs baseline: 18.3052x; 1.1185x over previous
//
#include <hip/hip_runtime.h>
#include <hip/hip_bf16.h>
#include <math.h>

#define HIDDEN 256
#define SEQ 2048
#define BATCH 64
#define INSZ 128
#define OUTSZ 64
#define DTC 0.05f

typedef _Float16 h2 __attribute__((ext_vector_type(2)));

// ---------------- K0: complexity net + alphas ----------------
__global__ __launch_bounds__(1024) void prep_kernel(
    const float* __restrict__ x, const float* __restrict__ cw1, const float* __restrict__ cb1,
    const float* __restrict__ cw2, const float* __restrict__ cb2,
    const float* __restrict__ tau_b, const float* __restrict__ tmw, const float* __restrict__ tmb,
    float* __restrict__ alphas)   // [3][64]
{
    __shared__ float p_lds[8][128];
    __shared__ float xm[128];
    __shared__ float t1[64];
    int b = blockIdx.x;
    int tid = threadIdx.x;
    int c = tid & 127, sh = tid >> 7;
    const float* xb = x + (size_t)b * SEQ * INSZ;
    float s = 0.f;
    for (int t = sh * 256; t < (sh + 1) * 256; ++t) s += xb[(size_t)t * INSZ + c];
    p_lds[sh][c] = s;
    __syncthreads();
    if (tid < 128) {
        float m = 0.f;
        #pragma unroll
        for (int i = 0; i < 8; ++i) m += p_lds[i][tid];
        xm[tid] = m / (float)SEQ;
    }
    __syncthreads();
    if (tid < 64) {
        float acc = cb1[tid];
        for (int k = 0; k < 128; ++k) acc += xm[k] * cw1[tid * 128 + k];
        t1[tid] = fmaxf(acc, 0.f);
    }
    __syncthreads();
    if (tid == 0) {
        float acc = cb2[0];
        for (int k = 0; k < 64; ++k) acc += t1[k] * cw2[k];
        float comp = 1.f / (1.f + expf(-acc));
        for (int i = 0; i < 3; ++i) {
            float lg[4], mx = -1e30f;
            for (int j = 0; j < 4; ++j) { lg[j] = comp * tmw[i * 4 + j] + tmb[i * 4 + j]; mx = fmaxf(mx, lg[j]); }
            float den = 0.f;
            for (int j = 0; j < 4; ++j) { lg[j] = expf(lg[j] - mx); den += lg[j]; }
            float mt = 0.f;
            for (int j = 0; j < 4; ++j) mt += tau_b[i * 4 + j] * (lg[j] / den);
            alphas[i * 64 + b] = expf(-DTC / mt);
        }
    }
}

// ---------------- Wf = W_in0 @ pw  (256x128), bf = W_in0 @ pb + bias0 ----------------
__global__ __launch_bounds__(128) void wf_kernel(
    const float* __restrict__ W_in0, const float* __restrict__ pw,
    const float* __restrict__ pb, const float* __restrict__ bias0,
    float* __restrict__ Wf, float* __restrict__ bf)
{
    __shared__ float wrow[256];
    int j = blockIdx.x, k = threadIdx.x;
    for (int m = k; m < 256; m += 128) wrow[m] = W_in0[j * 256 + m];
    __syncthreads();
    float s = 0.f;
    for (int m = 0; m < 256; ++m) s = fmaf(wrow[m], pw[m * 128 + k], s);
    Wf[j * 128 + k] = s;
    if (k == 0) {
        float sb = bias0[j];
        for (int m = 0; m < 256; ++m) sb = fmaf(wrow[m], pb[m], sb);
        bf[j] = sb;
    }
}

// ---------------- streaming register-weight GEMM (unchanged, fp32) ----------------
template<int KQ, int NR>
__global__ __launch_bounds__(512) void gemm_stream(
    const float* A, const float* __restrict__ W, const float* __restrict__ bias,
    float* C, int rows_per_wg)
{
    constexpr int K = KQ * 64;
    constexpr int JB = 8 / KQ;
    __shared__ float a_lds[4 * K];
    __shared__ float p_lds[KQ][4][256];
    __shared__ float bias_l[256];
    int tid = threadIdx.x;
    int w = tid >> 6, l = tid & 63;
    int q = w % KQ, jb = w / KQ;

    float4 wr[NR][16];
    #pragma unroll
    for (int r = 0; r < NR; ++r) {
        int j = jb * 64 + l + r * (JB * 64);
        const float4* wp = (const float4*)(W + (size_t)j * K + q * 64);
        #pragma unroll
        for (int m = 0; m < 16; ++m) wr[r][m] = wp[m];
    }
    if (tid < 256) bias_l[tid] = bias[tid];

    size_t row0 = (size_t)blockIdx.x * rows_per_wg;
    for (int it = 0; it < rows_per_wg; it += 4) {
        size_t m0 = row0 + it;
        __syncthreads();
        #pragma unroll
        for (int e = 0; e < K / 128; ++e)
            a_lds[tid + e * 512] = A[m0 * K + tid + e * 512];
        __syncthreads();

        float acc[4][NR];
        #pragma unroll
        for (int r4 = 0; r4 < 4; ++r4)
            #pragma unroll
            for (int r = 0; r < NR; ++r) acc[r4][r] = 0.f;

        #pragma unroll
        for (int r4 = 0; r4 < 4; ++r4) {
            const float4* hp = (const float4*)(a_lds + r4 * K + q * 64);
            #pragma unroll
            for (int m = 0; m < 16; ++m) {
                float4 hv = hp[m];
                #pragma unroll
                for (int r = 0; r < NR; ++r) {
                    acc[r4][r] = fmaf(wr[r][m].x, hv.x, acc[r4][r]);
                    acc[r4][r] = fmaf(wr[r][m].y, hv.y, acc[r4][r]);
                    acc[r4][r] = fmaf(wr[r][m].z, hv.z, acc[r4][r]);
                    acc[r4][r] = fmaf(wr[r][m].w, hv.w, acc[r4][r]);
                }
            }
        }
        #pragma unroll
        for (int r4 = 0; r4 < 4; ++r4)
            #pragma unroll
            for (int r = 0; r < NR; ++r)
                p_lds[q][r4][jb * 64 + l + r * (JB * 64)] = acc[r4][r];
        __syncthreads();
        if (tid < 256) {
            #pragma unroll
            for (int r4 = 0; r4 < 4; ++r4) {
                float s2 = bias_l[tid];
                #pragma unroll
                for (int qq = 0; qq < KQ; ++qq) s2 += p_lds[qq][r4][tid];
                C[(m0 + r4) * 256 + tid] = s2;
            }
        }
    }
}

__device__ __forceinline__ float fast_tanh(float x) {
    float ex = __expf(2.f * x);                 // v_exp based
    float r = __builtin_amdgcn_rcpf(ex + 1.f);  // v_rcp_f32
    return 1.f - 2.f * r;                       // ex=inf -> 1, ex=0 -> -1
}

// cross-lane add helpers: xor1/xor2 on VALU (DPP quad_perm) — no LDS pipe
__device__ __forceinline__ float dpp_add_xor1(float v) {
    int x = __builtin_amdgcn_update_dpp(0, __builtin_bit_cast(int, v), 0xB1, 0xF, 0xF, false); // quad_perm [1,0,3,2]
    return v + __builtin_bit_cast(float, x);
}
__device__ __forceinline__ float dpp_add_xor2(float v) {
    int x = __builtin_amdgcn_update_dpp(0, __builtin_bit_cast(int, v), 0x4E, 0xF, 0xF, false); // quad_perm [2,3,0,1]
    return v + __builtin_bit_cast(float, x);
}

#if __has_builtin(__builtin_amdgcn_fdot2)
#define FDOT2(a, b, c) __builtin_amdgcn_fdot2((a), (b), (c), false)
#else
#define FDOT2(a, b, c) fmaf((float)(a).x, (float)(b).x, fmaf((float)(a).y, (float)(b).y, (c)))
#endif

// ---------------- scan: 256 threads, thread tid owns output o=tid ----------------
// group g = tid>>2 (outputs 4g..4g+3), k-seg kq = tid&3 (k in [64kq, 64kq+64))
// 4-lane DPP-only reduce (xor1+xor2), ONE 4-wave barrier per step.
// h16 seg stride 144B: seg bases at words 36*kq mod 32 = {0,4,8,12} -> conflict-free
// broadcast reads (16 lanes share each address).
__global__ __launch_bounds__(256, 1) void scan_kernel(
    float* buf,                       // [B][S][256]: in = ext, out = h_seq (in place)
    const float* __restrict__ W_rec,  // [256][256]
    const float* __restrict__ alphas, // [64]
    float* __restrict__ h_carry,      // [64][256]
    int layer, int write_all)
{
    __shared__ alignas(16) unsigned short h16[2][4 * 72];  // 2 x 576B
    int b = blockIdx.x;
    int tid = threadIdx.x;
    int g = tid >> 2;       // 0..63
    int kq = tid & 3;       // 0..3
    int j = kq;             // output within group this lane finalizes
    int o = tid;            // == g*4 + j

    // weights rows 4g..4g+3, cols [64kq, 64kq+64), as 32 half2 per row = 128 VGPR
    h2 wh[4][32];
    #pragma unroll
    for (int jj = 0; jj < 4; ++jj) {
        const float4* wp = (const float4*)(W_rec + (size_t)(g * 4 + jj) * 256 + kq * 64);
        #pragma unroll
        for (int m = 0; m < 16; ++m) {
            float4 wv = wp[m];
            wh[jj][2 * m]     = __builtin_bit_cast(h2, __builtin_amdgcn_cvt_pkrtz(wv.x, wv.y));
            wh[jj][2 * m + 1] = __builtin_bit_cast(h2, __builtin_amdgcn_cvt_pkrtz(wv.z, wv.w));
        }
    }

    float alpha = alphas[b];
    float onema = 1.f - alpha;
    float* bb = buf + (size_t)b * SEQ * HIDDEN;

    float h_reg = (layer == 0) ? 0.f : h_carry[b * 256 + o];
    char* hbase = (char*)&h16[0][0];
    // initial h into buffer 0: seg o>>6, slot o&63
    *(_Float16*)(hbase + (o >> 6) * 144 + (o & 63) * 2) = (_Float16)h_reg;
    float e_cur = bb[o];                       // ext[0]
    float e_n1  = bb[(size_t)1 * HIDDEN + o];  // ext[1]
    __syncthreads();

    int cur = 0;
    for (int t = 0; t < SEQ; ++t) {
        float e_n2 = 0.f;
        if (t + 2 < SEQ) e_n2 = bb[(size_t)(t + 2) * HIDDEN + o];  // 2-ahead prefetch

        // read 64 f16 of h (this thread's k-segment): 8 x ds_read_b128, broadcast x16
        const uint4* hp = (const uint4*)(hbase + cur * 576 + kq * 144);
        float a0 = 0.f, a1 = 0.f, a2 = 0.f, a3 = 0.f;
        #pragma unroll
        for (int m = 0; m < 8; ++m) {
            uint4 q = hp[m];
            h2 hv0 = __builtin_bit_cast(h2, q.x);
            h2 hv1 = __builtin_bit_cast(h2, q.y);
            h2 hv2 = __builtin_bit_cast(h2, q.z);
            h2 hv3 = __builtin_bit_cast(h2, q.w);
            a0 = FDOT2(wh[0][4 * m], hv0, a0); a0 = FDOT2(wh[0][4 * m + 1], hv1, a0);
            a0 = FDOT2(wh[0][4 * m + 2], hv2, a0); a0 = FDOT2(wh[0][4 * m + 3], hv3, a0);
            a1 = FDOT2(wh[1][4 * m], hv0, a1); a1 = FDOT2(wh[1][4 * m + 1], hv1, a1);
            a1 = FDOT2(wh[1][4 * m + 2], hv2, a1); a1 = FDOT2(wh[1][4 * m + 3], hv3, a1);
            a2 = FDOT2(wh[2][4 * m], hv0, a2); a2 = FDOT2(wh[2][4 * m + 1], hv1, a2);
            a2 = FDOT2(wh[2][4 * m + 2], hv2, a2); a2 = FDOT2(wh[2][4 * m + 3], hv3, a2);
            a3 = FDOT2(wh[3][4 * m], hv0, a3); a3 = FDOT2(wh[3][4 * m + 1], hv1, a3);
            a3 = FDOT2(wh[3][4 * m + 2], hv2, a3); a3 = FDOT2(wh[3][4 * m + 3], hv3, a3);
        }
        // reduce over the 4 k-segments: 2 DPP levels, no LDS
        a0 = dpp_add_xor1(a0); a1 = dpp_add_xor1(a1); a2 = dpp_add_xor1(a2); a3 = dpp_add_xor1(a3);
        a0 = dpp_add_xor2(a0); a1 = dpp_add_xor2(a1); a2 = dpp_add_xor2(a2); a3 = dpp_add_xor2(a3);
        float acc = (j == 0) ? a0 : (j == 1) ? a1 : (j == 2) ? a2 : a3;

        float act = fast_tanh(acc + e_cur);
        h_reg = alpha * h_reg + onema * act;
        *(_Float16*)(hbase + (cur ^ 1) * 576 + (o >> 6) * 144 + (o & 63) * 2) = (_Float16)h_reg;
        if (write_all) bb[(size_t)t * HIDDEN + o] = h_reg;   // in-place h over consumed ext
        __syncthreads();                                      // ONE 4-wave barrier per step
        cur ^= 1;
        e_cur = e_n1;
        e_n1 = e_n2;
    }
    h_carry[b * 256 + o] = h_reg;
}

// ---------------- final projection from h_carry ----------------
__global__ __launch_bounds__(256) void outproj_kernel(
    const float* __restrict__ h_carry, const float* __restrict__ ow, const float* __restrict__ ob,
    float* __restrict__ out)
{
    __shared__ float h_l[256];
    __shared__ float p_lds[4][64];
    int b = blockIdx.x;
    int tid = threadIdx.x;
    h_l[tid] = h_carry[b * 256 + tid];
    __syncthreads();
    int o = tid & 63, qq = tid >> 6;
    float s = 0.f;
    const float4* wp = (const float4*)(ow + o * 256 + qq * 64);
    const float4* hp = (const float4*)(h_l + qq * 64);
    #pragma unroll
    for (int m = 0; m < 16; ++m) {
        float4 wv = wp[m]; float4 hv = hp[m];
        s = fmaf(wv.x, hv.x, s); s = fmaf(wv.y, hv.y, s);
        s = fmaf(wv.z, hv.z, s); s = fmaf(wv.w, hv.w, s);
    }
    p_lds[qq][o] = s;
    __syncthreads();
    if (tid < 64)
        out[b * 64 + tid] = p_lds[0][tid] + p_lds[1][tid] + p_lds[2][tid] + p_lds[3][tid] + ob[tid];
}

extern "C" void kernel_launch(void* const* d_in, const int* in_sizes, int n_in,
                              void* d_out, int out_size, void* d_ws, size_t ws_size,
                              hipStream_t stream)
{
    const float* x     = (const float*)d_in[0];
    const float* cw1   = (const float*)d_in[1];
    const float* cb1   = (const float*)d_in[2];
    const float* cw2   = (const float*)d_in[3];
    const float* cb2   = (const float*)d_in[4];
    const float* pw    = (const float*)d_in[5];
    const float* pb    = (const float*)d_in[6];
    const float* W_rec = (const float*)d_in[7];
    const float* W_in  = (const float*)d_in[8];
    const float* bias  = (const float*)d_in[9];
    const float* tau_b = (const float*)d_in[10];
    const float* tmw   = (const float*)d_in[11];
    const float* tmb   = (const float*)d_in[12];
    const float* ow    = (const float*)d_in[13];
    const float* ob    = (const float*)d_in[14];
    float* out = (float*)d_out;

    char* ws = (char*)d_ws;
    float* alphas  = (float*)ws;                       // 192 f
    float* h_carry = (float*)(ws + 4096);              // 64*256 f
    float* bf      = (float*)(ws + 69632);             // 256 f
    float* Wf      = (float*)(ws + 70656);             // 256*128 f
    float* buf     = (float*)(ws + 1048576);           // [64][2048][256] f32 = 134.2MB

    const int M = BATCH * SEQ;          // 131072 rows
    const int ROWS_PER_WG = M / 256;    // 512

    prep_kernel<<<64, 1024, 0, stream>>>(x, cw1, cb1, cw2, cb2, tau_b, tmw, tmb, alphas);
    wf_kernel<<<256, 128, 0, stream>>>(W_in, pw, pb, bias, Wf, bf);

    // layer 0 ext = x @ Wf.T + bf  (input projection fused away)
    gemm_stream<2, 1><<<256, 512, 0, stream>>>(x, Wf, bf, buf, ROWS_PER_WG);
    scan_kernel<<<64, 256, 0, stream>>>(buf, W_rec, alphas, h_carry, 0, 1);

    gemm_stream<4, 2><<<256, 512, 0, stream>>>(buf, W_in + (size_t)1 * HIDDEN * HIDDEN,
                                               bias + 1 * HIDDEN, buf, ROWS_PER_WG);
    scan_kernel<<<64, 256, 0, stream>>>(buf, W_rec + (size_t)1 * HIDDEN * HIDDEN,
                                        alphas + 64, h_carry, 1, 1);

    gemm_stream<4, 2><<<256, 512, 0, stream>>>(buf, W_in + (size_t)2 * HIDDEN * HIDDEN,
                                               bias + 2 * HIDDEN, buf, ROWS_PER_WG);
    scan_kernel<<<64, 256, 0, stream>>>(buf, W_rec + (size_t)2 * HIDDEN * HIDDEN,
                                        alphas + 128, h_carry, 2, 0);

    outproj_kernel<<<64, 256, 0, stream>>>(h_carry, ow, ob, out);
}